// Round 13
// baseline (548.798 us; speedup 1.0000x reference)
//
#include <hip/hip_runtime.h>
#include <math.h>

#define BB 4
#define NN 2048
#define KK 20
#define INFPK 0xFFFFFFFFFFFFFFFFull

static __device__ __forceinline__ float lrelu(float z) {
    return z >= 0.f ? z : 0.2f * z;
}

// 64-bit full-wave min via paired 32-bit DPP (row_shr 1,2,4,8 + row_bcast 15,31),
// broadcast via readlane 63. Validated on this HW in R7-R12 (passed).
template<int CTRL>
static __device__ __forceinline__ unsigned long long dpp_min64_step(unsigned long long v) {
    unsigned lo = (unsigned)__builtin_amdgcn_update_dpp(
        (int)0xFFFFFFFFu, (int)(unsigned)v, CTRL, 0xF, 0xF, false);
    unsigned hi = (unsigned)__builtin_amdgcn_update_dpp(
        (int)0xFFFFFFFFu, (int)(unsigned)(v >> 32), CTRL, 0xF, 0xF, false);
    unsigned long long t = ((unsigned long long)hi << 32) | lo;
    return t < v ? t : v;
}
static __device__ __forceinline__ unsigned long long wave_min64_bcast(unsigned long long v) {
    v = dpp_min64_step<0x111>(v);
    v = dpp_min64_step<0x112>(v);
    v = dpp_min64_step<0x114>(v);
    v = dpp_min64_step<0x118>(v);
    v = dpp_min64_step<0x142>(v);
    v = dpp_min64_step<0x143>(v);
    unsigned lo = (unsigned)__builtin_amdgcn_readlane((int)(unsigned)v, 63);
    unsigned hi = (unsigned)__builtin_amdgcn_readlane((int)(unsigned)(v >> 32), 63);
    return ((unsigned long long)hi << 32) | lo;
}

// ---------------- sq: per-point squared norm (identical chain to R2-R9) -----
template<int C>
__global__ __launch_bounds__(256) void sq_kernel(const float* __restrict__ x,
                                                 float* __restrict__ sq) {
    int i = blockIdx.x * 256 + threadIdx.x;
    if (i >= BB * NN) return;
    int b = i / NN, n = i - b * NN;
    const float* xb = x + (size_t)b * C * NN + n;
    float s = 0.f;
    #pragma unroll
    for (int c = 0; c < C; ++c) {
        float v = xb[(size_t)c * NN];
        s = fmaf(v, v, s);
    }
    sq[i] = s;
}

// ---------------- knn: top-20 smallest distance indices (R9 structure) ------
// Block = 512 threads (8 waves) = (b, 8 queries); wave owns ONE query.
// Distance: thread t owns j in {4t..4t+3}; ONE float4 global load per channel;
// scalar xq LDS reads (R9 config — measured fastest: 94us @C=128; the R10 sq
// fusion/b128-xq variants measured slower). Distances bit-identical to all
// passing rounds.
// Selection: per-lane sorted top-4 u64 queue + single DPP-min chain per round
// (R8-R12 proven). u64 min on pk=(key<<12)|j == exact (d,j) lexicographic.
template<int C>
__global__ __launch_bounds__(512) void knn_kernel(const float* __restrict__ x,
                                                  const float* __restrict__ sq,
                                                  int* __restrict__ idx) {
    const int QT = 8;
    __shared__ unsigned dl[QT][NN];   // 64 KB swizzled keys
    __shared__ float xq[QT][C];
    __shared__ float sqq[QT];
    int blk = blockIdx.x;
    int b = blk / (NN / QT);
    int q0 = (blk - b * (NN / QT)) * QT;
    int t = threadIdx.x;
    int lane = t & 63, wid = t >> 6;

    const float* xb = x + (size_t)b * C * NN;
    for (int e = t; e < QT * C; e += 512) {
        int q = e / C, c = e - q * C;
        xq[q][c] = xb[(size_t)c * NN + q0 + q];
    }
    if (t < QT) sqq[t] = sq[b * NN + q0 + t];
    __syncthreads();

    float acc[QT][4];
    #pragma unroll
    for (int q = 0; q < QT; ++q)
        #pragma unroll
        for (int u = 0; u < 4; ++u) acc[q][u] = 0.f;

    for (int c = 0; c < C; ++c) {
        float4 xj = *(const float4*)&xb[(size_t)c * NN + 4 * t];
        #pragma unroll
        for (int q = 0; q < QT; ++q) {
            float xqc = xq[q][c];
            acc[q][0] = fmaf(xqc, xj.x, acc[q][0]);
            acc[q][1] = fmaf(xqc, xj.y, acc[q][1]);
            acc[q][2] = fmaf(xqc, xj.z, acc[q][2]);
            acc[q][3] = fmaf(xqc, xj.w, acc[q][3]);
        }
    }
    float4 sqj = *(const float4*)&sq[b * NN + 4 * t];
    float sqju[4] = {sqj.x, sqj.y, sqj.z, sqj.w};

    // d = sq_i + sq_j - 2*inner (bit-identical expression), monotone u32 key,
    // stored swizzled: j=4t+u -> word ((t>>3)<<5) | (((t^(t>>3))&7)<<2) | u
    int wbase = ((t >> 3) << 5) | (((t ^ (t >> 3)) & 7) << 2);
    #pragma unroll
    for (int q = 0; q < QT; ++q) {
        float sqi = sqq[q];
        uint4 kv;
        unsigned ks[4];
        #pragma unroll
        for (int u = 0; u < 4; ++u) {
            float d = sqi + sqju[u] - 2.f * acc[q][u];
            unsigned v = __float_as_uint(d);
            ks[u] = v ^ ((unsigned)((int)v >> 31) | 0x80000000u);
        }
        kv.x = ks[0]; kv.y = ks[1]; kv.z = ks[2]; kv.w = ks[3];
        *(uint4*)&dl[q][wbase] = kv;
    }
    __syncthreads();

    unsigned* dq = &dl[wid][0];
    int r7 = lane & 7;
    int lanebase = lane << 5;

    unsigned long long h0 = INFPK, h1 = INFPK, h2 = INFPK, h3 = INFPK;

#define PK_INS(KEY, LO) {                                                     \
        unsigned long long v =                                                \
            ((unsigned long long)(KEY) << 12) | (unsigned)(lanebase + (LO));  \
        if (v < h3) {                                                         \
            unsigned long long nh3 = h2 > v ? h2 : v;                         \
            unsigned long long t2  = h2 < v ? h2 : v;                         \
            unsigned long long nh2 = h1 > t2 ? h1 : t2;                       \
            unsigned long long t1  = h1 < v ? h1 : v;                         \
            unsigned long long nh1 = h0 > t1 ? h0 : t1;                       \
            unsigned long long nh0 = h0 < v ? h0 : v;                         \
            h0 = nh0; h1 = nh1; h2 = nh2; h3 = nh3;                           \
        } }
#define PK_INS_THR(KEY, LO) {                                                 \
        unsigned long long v =                                                \
            ((unsigned long long)(KEY) << 12) | (unsigned)(lanebase + (LO));  \
        if (v > thr && v < h3) {                                              \
            unsigned long long nh3 = h2 > v ? h2 : v;                         \
            unsigned long long t2  = h2 < v ? h2 : v;                         \
            unsigned long long nh2 = h1 > t2 ? h1 : t2;                       \
            unsigned long long t1  = h1 < v ? h1 : v;                         \
            unsigned long long nh1 = h0 > t1 ? h0 : t1;                       \
            unsigned long long nh0 = h0 < v ? h0 : v;                         \
            h0 = nh0; h1 = nh1; h2 = nh2; h3 = nh3;                           \
        } }
#define CHUNK_RD(c) uint4 V##c = *(const uint4*)(dq + lanebase + (((c) ^ r7) << 2));
#define CHUNK_INS(c)     { PK_INS(V##c.x, 4*(c)+0) PK_INS(V##c.y, 4*(c)+1)        \
                           PK_INS(V##c.z, 4*(c)+2) PK_INS(V##c.w, 4*(c)+3) }
#define CHUNK_INS_THR(c) { PK_INS_THR(V##c.x, 4*(c)+0) PK_INS_THR(V##c.y, 4*(c)+1) \
                           PK_INS_THR(V##c.z, 4*(c)+2) PK_INS_THR(V##c.w, 4*(c)+3) }

    {   // build: one pass over the lane's 32 candidates
        CHUNK_RD(0) CHUNK_RD(1) CHUNK_RD(2) CHUNK_RD(3)
        CHUNK_RD(4) CHUNK_RD(5) CHUNK_RD(6) CHUNK_RD(7)
        CHUNK_INS(0) CHUNK_INS(1) CHUNK_INS(2) CHUNK_INS(3)
        CHUNK_INS(4) CHUNK_INS(5) CHUNK_INS(6) CHUNK_INS(7)
    }

    int* orow = idx + (size_t)(b * NN + q0 + wid) * KK;
    unsigned long long thr = 0;
    int popped = 0;
    #pragma unroll 1
    for (int rr = 0; rr < KK; ++rr) {
        unsigned long long g = wave_min64_bcast(h0);
        if (lane == 0) orow[rr] = (int)(g & 0xFFFu);
        if (h0 == g) {
            thr = g;
            ++popped;
            h0 = h1; h1 = h2; h2 = h3; h3 = INFPK;
            if (h0 == INFPK && popped < 32) {   // rare refill
                CHUNK_RD(0) CHUNK_RD(1) CHUNK_RD(2) CHUNK_RD(3)
                CHUNK_RD(4) CHUNK_RD(5) CHUNK_RD(6) CHUNK_RD(7)
                CHUNK_INS_THR(0) CHUNK_INS_THR(1) CHUNK_INS_THR(2) CHUNK_INS_THR(3)
                CHUNK_INS_THR(4) CHUNK_INS_THR(5) CHUNK_INS_THR(6) CHUNK_INS_THR(7)
            }
        }
    }
#undef PK_INS
#undef PK_INS_THR
#undef CHUNK_RD
#undef CHUNK_INS
#undef CHUNK_INS_THR
}

// ---------------- p/t: p = Wn·x, t = (Wc-Wn)·x ----------------
template<int C, int OT>
__global__ __launch_bounds__(256) void pt_kernel(const float* __restrict__ x,
                                                 const float* __restrict__ W,
                                                 float* __restrict__ p,
                                                 float* __restrict__ tt,
                                                 int O) {
    const int NB = NN / 256;
    int blk = blockIdx.x;
    int nb = blk % NB;
    int rest = blk / NB;
    int nob = O / OT;
    int ob = rest % nob;
    int b = rest / nob;
    int t = threadIdx.x;
    int n = nb * 256 + t;
    __shared__ float wn[OT][C], wd[OT][C];
    for (int e = t; e < OT * C; e += 256) {
        int o = e / C, c = e - o * C;
        float a = W[(size_t)(ob * OT + o) * (2 * C) + c];
        float b2 = W[(size_t)(ob * OT + o) * (2 * C) + C + c];
        wn[o][c] = a;
        wd[o][c] = b2 - a;
    }
    __syncthreads();
    float ap[OT], at[OT];
    #pragma unroll
    for (int o = 0; o < OT; ++o) { ap[o] = 0.f; at[o] = 0.f; }
    const float* xb = x + (size_t)b * C * NN + n;
    for (int c = 0; c < C; ++c) {
        float xv = xb[(size_t)c * NN];
        #pragma unroll
        for (int o = 0; o < OT; ++o) {
            ap[o] = fmaf(wn[o][c], xv, ap[o]);
            at[o] = fmaf(wd[o][c], xv, at[o]);
        }
    }
    size_t base = ((size_t)b * O + ob * OT) * NN + n;
    #pragma unroll
    for (int o = 0; o < OT; ++o) {
        p[base + (size_t)o * NN] = ap[o];
        tt[base + (size_t)o * NN] = at[o];
    }
}

// ---------------- edge max ----------------
__global__ __launch_bounds__(256) void edge_kernel(const float* __restrict__ p,
                                                   const float* __restrict__ tt,
                                                   const int* __restrict__ idx,
                                                   const float* __restrict__ g,
                                                   const float* __restrict__ be,
                                                   float* __restrict__ out, int O) {
    int b = blockIdx.x / O, o = blockIdx.x - b * O;
    __shared__ float pl[NN];
    const float* pr = p + ((size_t)b * O + o) * NN;
    for (int e = threadIdx.x * 4; e < NN; e += 1024)
        *(float4*)&pl[e] = *(const float4*)&pr[e];
    __syncthreads();
    float scale = g[o] / sqrtf(1.f + 1e-5f);
    float beta = be[o];
    const float* tr = tt + ((size_t)b * O + o) * NN;
    float* orow = out + ((size_t)b * O + o) * NN;
    for (int i = threadIdx.x; i < NN; i += 256) {
        float ti = tr[i];
        const int4* ir4 = (const int4*)(idx + (size_t)(b * NN + i) * KK);
        int4 w0 = ir4[0], w1 = ir4[1], w2 = ir4[2], w3 = ir4[3], w4 = ir4[4];
        float m = -__builtin_inff();
        int js[20] = {w0.x, w0.y, w0.z, w0.w, w1.x, w1.y, w1.z, w1.w,
                      w2.x, w2.y, w2.z, w2.w, w3.x, w3.y, w3.z, w3.w,
                      w4.x, w4.y, w4.z, w4.w};
        #pragma unroll
        for (int k = 0; k < KK; ++k) {
            float y = pl[js[k]] + ti;
            m = fmaxf(m, lrelu(fmaf(scale, y, beta)));
        }
        orow[i] = m;
    }
}

// ---------------- transpose W5 [1024][256] -> W5T [256][1024] ----------------
__global__ __launch_bounds__(256) void transpose_kernel(const float* __restrict__ W,
                                                        float* __restrict__ WT) {
    __shared__ float tile[32][33];
    int c0 = blockIdx.x * 32, o0 = blockIdx.y * 32;
    int tx = threadIdx.x, ty = threadIdx.y;
    #pragma unroll
    for (int i = 0; i < 32; i += 8)
        tile[ty + i][tx] = W[(size_t)(o0 + ty + i) * 256 + c0 + tx];
    __syncthreads();
    #pragma unroll
    for (int i = 0; i < 32; i += 8)
        WT[(size_t)(c0 + ty + i) * 1024 + o0 + tx] = tile[tx][ty + i];
}

// ---------------- final: 128x128 block tile, 8x8/thread (R12, proven) -------
__global__ __launch_bounds__(256) void final_kernel(const float* __restrict__ x4,
                                                    const float* __restrict__ W5T,
                                                    const float* __restrict__ g,
                                                    const float* __restrict__ be,
                                                    float* __restrict__ partial) {
    const int CC = 256;
    __shared__ float xs[32][128];
    __shared__ float ws[32][128];
    int blk = blockIdx.x;
    int nb = blk & 15;
    int ob = (blk >> 4) & 7;
    int b  = blk >> 7;
    int t = threadIdx.x;
    int tn = t & 15, to = t >> 4;

    float acc[8][8];
    #pragma unroll
    for (int i = 0; i < 8; ++i)
        #pragma unroll
        for (int j = 0; j < 8; ++j) acc[i][j] = 0.f;

    for (int c0 = 0; c0 < CC; c0 += 32) {
        __syncthreads();
        #pragma unroll
        for (int e = t * 4; e < 32 * 128; e += 1024) {
            int c = e >> 7, n = e & 127;
            *(float4*)&xs[c][n] =
                *(const float4*)&x4[((size_t)b * CC + c0 + c) * NN + nb * 128 + n];
        }
        #pragma unroll
        for (int e = t * 4; e < 32 * 128; e += 1024) {
            int c = e >> 7, o = e & 127;
            *(float4*)&ws[c][o] =
                *(const float4*)&W5T[(size_t)(c0 + c) * 1024 + ob * 128 + o];
        }
        __syncthreads();
        for (int c = 0; c < 32; ++c) {
            float4 xv0 = *(float4*)&xs[c][tn * 4];
            float4 xv1 = *(float4*)&xs[c][64 + tn * 4];
            float4 wv0 = *(float4*)&ws[c][to * 4];
            float4 wv1 = *(float4*)&ws[c][64 + to * 4];
            float xn[8] = {xv0.x, xv0.y, xv0.z, xv0.w, xv1.x, xv1.y, xv1.z, xv1.w};
            float wo[8] = {wv0.x, wv0.y, wv0.z, wv0.w, wv1.x, wv1.y, wv1.z, wv1.w};
            #pragma unroll
            for (int i = 0; i < 8; ++i)
                #pragma unroll
                for (int j = 0; j < 8; ++j)
                    acc[i][j] = fmaf(wo[i], xn[j], acc[i][j]);
        }
    }

    float rs = 1.f / sqrtf(1.f + 1e-5f);
    #pragma unroll
    for (int i = 0; i < 8; ++i) {
        int o = ob * 128 + ((i < 4) ? (to * 4 + i) : (64 + to * 4 + i - 4));
        float scale = g[o] * rs, beta = be[o];
        float m = -__builtin_inff();
        #pragma unroll
        for (int j = 0; j < 8; ++j)
            m = fmaxf(m, lrelu(fmaf(scale, acc[i][j], beta)));
        #pragma unroll
        for (int off = 8; off >= 1; off >>= 1)
            m = fmaxf(m, __shfl_xor(m, off));
        if (tn == 0)
            partial[(size_t)(nb * BB + b) * 1024 + o] = m;
    }
}

__global__ __launch_bounds__(256) void reduce16_kernel(const float* __restrict__ partial,
                                                       float* __restrict__ out) {
    int i = blockIdx.x * 256 + threadIdx.x;
    if (i >= BB * 1024) return;
    int b = i >> 10, o = i & 1023;
    float m = -__builtin_inff();
    #pragma unroll
    for (int nb = 0; nb < 16; ++nb)
        m = fmaxf(m, partial[(size_t)(nb * BB + b) * 1024 + o]);
    out[i] = m;
}

extern "C" void kernel_launch(void* const* d_in, const int* in_sizes, int n_in,
                              void* d_out, int out_size, void* d_ws, size_t ws_size,
                              hipStream_t stream) {
    const float* x  = (const float*)d_in[0];
    const float* W1 = (const float*)d_in[1];
    const float* g1 = (const float*)d_in[2];
    const float* b1 = (const float*)d_in[3];
    const float* W2 = (const float*)d_in[4];
    const float* g2 = (const float*)d_in[5];
    const float* b2 = (const float*)d_in[6];
    const float* W3 = (const float*)d_in[7];
    const float* g3 = (const float*)d_in[8];
    const float* b3 = (const float*)d_in[9];
    const float* W4 = (const float*)d_in[10];
    const float* g4 = (const float*)d_in[11];
    const float* b4 = (const float*)d_in[12];
    const float* W5 = (const float*)d_in[13];
    const float* g5 = (const float*)d_in[14];
    const float* b5 = (const float*)d_in[15];

    float* ws = (float*)d_ws;
    float* sqv     = ws;                       // 8192
    int*   idx     = (int*)(ws + 8192);        // 163840 ints
    float* x1      = ws + 8192 + 163840;       // 524288
    float* x2      = x1 + 524288;              // 524288
    float* x3      = x2 + 524288;              // 1048576
    float* x4      = x3 + 1048576;             // 2097152
    float* p       = x4 + 2097152;             // 2097152
    float* tt      = p + 2097152;              // 2097152
    float* W5T     = p;                        // reuse (dead after layer 4)
    float* partial = tt;                       // reuse

    dim3 blk(256), kblk(512);

    // ---- layer 1: C=3, O=64 ----
    sq_kernel<3><<<32, blk, 0, stream>>>(x, sqv);
    knn_kernel<3><<<BB * (NN / 8), kblk, 0, stream>>>(x, sqv, idx);
    pt_kernel<3, 16><<<BB * 4 * 8, blk, 0, stream>>>(x, W1, p, tt, 64);
    edge_kernel<<<BB * 64, blk, 0, stream>>>(p, tt, idx, g1, b1, x1, 64);

    // ---- layer 2: C=64, O=64 ----
    sq_kernel<64><<<32, blk, 0, stream>>>(x1, sqv);
    knn_kernel<64><<<BB * (NN / 8), kblk, 0, stream>>>(x1, sqv, idx);
    pt_kernel<64, 16><<<BB * 4 * 8, blk, 0, stream>>>(x1, W2, p, tt, 64);
    edge_kernel<<<BB * 64, blk, 0, stream>>>(p, tt, idx, g2, b2, x2, 64);

    // ---- layer 3: C=64, O=128 ----
    sq_kernel<64><<<32, blk, 0, stream>>>(x2, sqv);
    knn_kernel<64><<<BB * (NN / 8), kblk, 0, stream>>>(x2, sqv, idx);
    pt_kernel<64, 16><<<BB * 8 * 8, blk, 0, stream>>>(x2, W3, p, tt, 128);
    edge_kernel<<<BB * 128, blk, 0, stream>>>(p, tt, idx, g3, b3, x3, 128);

    // ---- layer 4: C=128, O=256 ----
    sq_kernel<128><<<32, blk, 0, stream>>>(x3, sqv);
    knn_kernel<128><<<BB * (NN / 8), kblk, 0, stream>>>(x3, sqv, idx);
    pt_kernel<128, 16><<<BB * 16 * 8, blk, 0, stream>>>(x3, W4, p, tt, 256);
    edge_kernel<<<BB * 256, blk, 0, stream>>>(p, tt, idx, g4, b4, x4, 256);

    // ---- layer 5: C=256, O=1024, fused max over n ----
    transpose_kernel<<<dim3(8, 32), dim3(32, 8), 0, stream>>>(W5, W5T);
    final_kernel<<<BB * 8 * 16, blk, 0, stream>>>(x4, W5T, g5, b5, partial);
    reduce16_kernel<<<16, blk, 0, stream>>>(partial, (float*)d_out);
}

// Round 14
// 544.652 us; speedup vs baseline: 1.0076x; 1.0076x over previous
//
#include <hip/hip_runtime.h>
#include <math.h>

#define BB 4
#define NN 2048
#define KK 20
#define INFPK 0xFFFFFFFFFFFFFFFFull

static __device__ __forceinline__ float lrelu(float z) {
    return z >= 0.f ? z : 0.2f * z;
}

// 64-bit full-wave min via paired 32-bit DPP (row_shr 1,2,4,8 + row_bcast 15,31),
// broadcast via readlane 63. Validated on this HW in R7-R13 (passed).
template<int CTRL>
static __device__ __forceinline__ unsigned long long dpp_min64_step(unsigned long long v) {
    unsigned lo = (unsigned)__builtin_amdgcn_update_dpp(
        (int)0xFFFFFFFFu, (int)(unsigned)v, CTRL, 0xF, 0xF, false);
    unsigned hi = (unsigned)__builtin_amdgcn_update_dpp(
        (int)0xFFFFFFFFu, (int)(unsigned)(v >> 32), CTRL, 0xF, 0xF, false);
    unsigned long long t = ((unsigned long long)hi << 32) | lo;
    return t < v ? t : v;
}
static __device__ __forceinline__ unsigned long long wave_min64_bcast(unsigned long long v) {
    v = dpp_min64_step<0x111>(v);
    v = dpp_min64_step<0x112>(v);
    v = dpp_min64_step<0x114>(v);
    v = dpp_min64_step<0x118>(v);
    v = dpp_min64_step<0x142>(v);
    v = dpp_min64_step<0x143>(v);
    unsigned lo = (unsigned)__builtin_amdgcn_readlane((int)(unsigned)v, 63);
    unsigned hi = (unsigned)__builtin_amdgcn_readlane((int)(unsigned)(v >> 32), 63);
    return ((unsigned long long)hi << 32) | lo;
}

// ---------------- sq: per-point squared norm (identical chain to R2-R13) ----
template<int C>
__global__ __launch_bounds__(256) void sq_kernel(const float* __restrict__ x,
                                                 float* __restrict__ sq) {
    int i = blockIdx.x * 256 + threadIdx.x;
    if (i >= BB * NN) return;
    int b = i / NN, n = i - b * NN;
    const float* xb = x + (size_t)b * C * NN + n;
    float s = 0.f;
    #pragma unroll
    for (int c = 0; c < C; ++c) {
        float v = xb[(size_t)c * NN];
        s = fmaf(v, v, s);
    }
    sq[i] = s;
}

// ---------------- knn: top-20 smallest distance indices ---------------------
// R13 structure (separate sq, 512 thr / 8 waves / QT=8, u64-queue + DPP-min
// selection) with ONE isolated change: xq read as broadcast ds_read_b128 per
// 4 channels (was 1024 scalar ds_read_b32 per thread — ~14% of issue). The
// per-(q,j) FMA chain remains ascending-c -> distances bit-identical.
template<int C>
__global__ __launch_bounds__(512, 2) void knn_kernel(const float* __restrict__ x,
                                                     const float* __restrict__ sq,
                                                     int* __restrict__ idx) {
    const int QT = 8;
    __shared__ unsigned dl[QT][NN];   // 64 KB swizzled keys
    __shared__ float xq[QT][C];
    __shared__ float sqq[QT];
    int blk = blockIdx.x;
    int b = blk / (NN / QT);
    int q0 = (blk - b * (NN / QT)) * QT;
    int t = threadIdx.x;
    int lane = t & 63, wid = t >> 6;

    const float* xb = x + (size_t)b * C * NN;
    for (int e = t; e < QT * C; e += 512) {
        int q = e / C, c = e - q * C;
        xq[q][c] = xb[(size_t)c * NN + q0 + q];
    }
    if (t < QT) sqq[t] = sq[b * NN + q0 + t];
    __syncthreads();

    float acc[QT][4];
    #pragma unroll
    for (int q = 0; q < QT; ++q)
        #pragma unroll
        for (int u = 0; u < 4; ++u) acc[q][u] = 0.f;

    if constexpr (C % 4 == 0) {
        for (int c4 = 0; c4 < C; c4 += 4) {
            float4 xj0 = *(const float4*)&xb[(size_t)(c4 + 0) * NN + 4 * t];
            float4 xj1 = *(const float4*)&xb[(size_t)(c4 + 1) * NN + 4 * t];
            float4 xj2 = *(const float4*)&xb[(size_t)(c4 + 2) * NN + 4 * t];
            float4 xj3 = *(const float4*)&xb[(size_t)(c4 + 3) * NN + 4 * t];
            #pragma unroll
            for (int q = 0; q < QT; ++q) {
                float4 xqv = *(const float4*)&xq[q][c4];   // broadcast b128
                acc[q][0] = fmaf(xqv.x, xj0.x, acc[q][0]);
                acc[q][1] = fmaf(xqv.x, xj0.y, acc[q][1]);
                acc[q][2] = fmaf(xqv.x, xj0.z, acc[q][2]);
                acc[q][3] = fmaf(xqv.x, xj0.w, acc[q][3]);
                acc[q][0] = fmaf(xqv.y, xj1.x, acc[q][0]);
                acc[q][1] = fmaf(xqv.y, xj1.y, acc[q][1]);
                acc[q][2] = fmaf(xqv.y, xj1.z, acc[q][2]);
                acc[q][3] = fmaf(xqv.y, xj1.w, acc[q][3]);
                acc[q][0] = fmaf(xqv.z, xj2.x, acc[q][0]);
                acc[q][1] = fmaf(xqv.z, xj2.y, acc[q][1]);
                acc[q][2] = fmaf(xqv.z, xj2.z, acc[q][2]);
                acc[q][3] = fmaf(xqv.z, xj2.w, acc[q][3]);
                acc[q][0] = fmaf(xqv.w, xj3.x, acc[q][0]);
                acc[q][1] = fmaf(xqv.w, xj3.y, acc[q][1]);
                acc[q][2] = fmaf(xqv.w, xj3.z, acc[q][2]);
                acc[q][3] = fmaf(xqv.w, xj3.w, acc[q][3]);
            }
        }
    } else {
        for (int c = 0; c < C; ++c) {
            float4 xj = *(const float4*)&xb[(size_t)c * NN + 4 * t];
            #pragma unroll
            for (int q = 0; q < QT; ++q) {
                float xqc = xq[q][c];
                acc[q][0] = fmaf(xqc, xj.x, acc[q][0]);
                acc[q][1] = fmaf(xqc, xj.y, acc[q][1]);
                acc[q][2] = fmaf(xqc, xj.z, acc[q][2]);
                acc[q][3] = fmaf(xqc, xj.w, acc[q][3]);
            }
        }
    }
    float4 sqj = *(const float4*)&sq[b * NN + 4 * t];
    float sqju[4] = {sqj.x, sqj.y, sqj.z, sqj.w};

    // d = sq_i + sq_j - 2*inner (bit-identical expression), monotone u32 key,
    // stored swizzled: j=4t+u -> word ((t>>3)<<5) | (((t^(t>>3))&7)<<2) | u
    int wbase = ((t >> 3) << 5) | (((t ^ (t >> 3)) & 7) << 2);
    #pragma unroll
    for (int q = 0; q < QT; ++q) {
        float sqi = sqq[q];
        uint4 kv;
        unsigned ks[4];
        #pragma unroll
        for (int u = 0; u < 4; ++u) {
            float d = sqi + sqju[u] - 2.f * acc[q][u];
            unsigned v = __float_as_uint(d);
            ks[u] = v ^ ((unsigned)((int)v >> 31) | 0x80000000u);
        }
        kv.x = ks[0]; kv.y = ks[1]; kv.z = ks[2]; kv.w = ks[3];
        *(uint4*)&dl[q][wbase] = kv;
    }
    __syncthreads();

    unsigned* dq = &dl[wid][0];
    int r7 = lane & 7;
    int lanebase = lane << 5;

    unsigned long long h0 = INFPK, h1 = INFPK, h2 = INFPK, h3 = INFPK;

#define PK_INS(KEY, LO) {                                                     \
        unsigned long long v =                                                \
            ((unsigned long long)(KEY) << 12) | (unsigned)(lanebase + (LO));  \
        if (v < h3) {                                                         \
            unsigned long long nh3 = h2 > v ? h2 : v;                         \
            unsigned long long t2  = h2 < v ? h2 : v;                         \
            unsigned long long nh2 = h1 > t2 ? h1 : t2;                       \
            unsigned long long t1  = h1 < v ? h1 : v;                         \
            unsigned long long nh1 = h0 > t1 ? h0 : t1;                       \
            unsigned long long nh0 = h0 < v ? h0 : v;                         \
            h0 = nh0; h1 = nh1; h2 = nh2; h3 = nh3;                           \
        } }
#define PK_INS_THR(KEY, LO) {                                                 \
        unsigned long long v =                                                \
            ((unsigned long long)(KEY) << 12) | (unsigned)(lanebase + (LO));  \
        if (v > thr && v < h3) {                                              \
            unsigned long long nh3 = h2 > v ? h2 : v;                         \
            unsigned long long t2  = h2 < v ? h2 : v;                         \
            unsigned long long nh2 = h1 > t2 ? h1 : t2;                       \
            unsigned long long t1  = h1 < v ? h1 : v;                         \
            unsigned long long nh1 = h0 > t1 ? h0 : t1;                       \
            unsigned long long nh0 = h0 < v ? h0 : v;                         \
            h0 = nh0; h1 = nh1; h2 = nh2; h3 = nh3;                           \
        } }
#define CHUNK_RD(c) uint4 V##c = *(const uint4*)(dq + lanebase + (((c) ^ r7) << 2));
#define CHUNK_INS(c)     { PK_INS(V##c.x, 4*(c)+0) PK_INS(V##c.y, 4*(c)+1)        \
                           PK_INS(V##c.z, 4*(c)+2) PK_INS(V##c.w, 4*(c)+3) }
#define CHUNK_INS_THR(c) { PK_INS_THR(V##c.x, 4*(c)+0) PK_INS_THR(V##c.y, 4*(c)+1) \
                           PK_INS_THR(V##c.z, 4*(c)+2) PK_INS_THR(V##c.w, 4*(c)+3) }

    {   // build: one pass over the lane's 32 candidates
        CHUNK_RD(0) CHUNK_RD(1) CHUNK_RD(2) CHUNK_RD(3)
        CHUNK_RD(4) CHUNK_RD(5) CHUNK_RD(6) CHUNK_RD(7)
        CHUNK_INS(0) CHUNK_INS(1) CHUNK_INS(2) CHUNK_INS(3)
        CHUNK_INS(4) CHUNK_INS(5) CHUNK_INS(6) CHUNK_INS(7)
    }

    int* orow = idx + (size_t)(b * NN + q0 + wid) * KK;
    unsigned long long thr = 0;
    int popped = 0;
    #pragma unroll 1
    for (int rr = 0; rr < KK; ++rr) {
        unsigned long long g = wave_min64_bcast(h0);
        if (lane == 0) orow[rr] = (int)(g & 0xFFFu);
        if (h0 == g) {
            thr = g;
            ++popped;
            h0 = h1; h1 = h2; h2 = h3; h3 = INFPK;
            if (h0 == INFPK && popped < 32) {   // rare refill
                CHUNK_RD(0) CHUNK_RD(1) CHUNK_RD(2) CHUNK_RD(3)
                CHUNK_RD(4) CHUNK_RD(5) CHUNK_RD(6) CHUNK_RD(7)
                CHUNK_INS_THR(0) CHUNK_INS_THR(1) CHUNK_INS_THR(2) CHUNK_INS_THR(3)
                CHUNK_INS_THR(4) CHUNK_INS_THR(5) CHUNK_INS_THR(6) CHUNK_INS_THR(7)
            }
        }
    }
#undef PK_INS
#undef PK_INS_THR
#undef CHUNK_RD
#undef CHUNK_INS
#undef CHUNK_INS_THR
}

// ---------------- p/t: p = Wn·x, t = (Wc-Wn)·x ----------------
template<int C, int OT>
__global__ __launch_bounds__(256) void pt_kernel(const float* __restrict__ x,
                                                 const float* __restrict__ W,
                                                 float* __restrict__ p,
                                                 float* __restrict__ tt,
                                                 int O) {
    const int NB = NN / 256;
    int blk = blockIdx.x;
    int nb = blk % NB;
    int rest = blk / NB;
    int nob = O / OT;
    int ob = rest % nob;
    int b = rest / nob;
    int t = threadIdx.x;
    int n = nb * 256 + t;
    __shared__ float wn[OT][C], wd[OT][C];
    for (int e = t; e < OT * C; e += 256) {
        int o = e / C, c = e - o * C;
        float a = W[(size_t)(ob * OT + o) * (2 * C) + c];
        float b2 = W[(size_t)(ob * OT + o) * (2 * C) + C + c];
        wn[o][c] = a;
        wd[o][c] = b2 - a;
    }
    __syncthreads();
    float ap[OT], at[OT];
    #pragma unroll
    for (int o = 0; o < OT; ++o) { ap[o] = 0.f; at[o] = 0.f; }
    const float* xb = x + (size_t)b * C * NN + n;
    for (int c = 0; c < C; ++c) {
        float xv = xb[(size_t)c * NN];
        #pragma unroll
        for (int o = 0; o < OT; ++o) {
            ap[o] = fmaf(wn[o][c], xv, ap[o]);
            at[o] = fmaf(wd[o][c], xv, at[o]);
        }
    }
    size_t base = ((size_t)b * O + ob * OT) * NN + n;
    #pragma unroll
    for (int o = 0; o < OT; ++o) {
        p[base + (size_t)o * NN] = ap[o];
        tt[base + (size_t)o * NN] = at[o];
    }
}

// ---------------- edge max ----------------
__global__ __launch_bounds__(256) void edge_kernel(const float* __restrict__ p,
                                                   const float* __restrict__ tt,
                                                   const int* __restrict__ idx,
                                                   const float* __restrict__ g,
                                                   const float* __restrict__ be,
                                                   float* __restrict__ out, int O) {
    int b = blockIdx.x / O, o = blockIdx.x - b * O;
    __shared__ float pl[NN];
    const float* pr = p + ((size_t)b * O + o) * NN;
    for (int e = threadIdx.x * 4; e < NN; e += 1024)
        *(float4*)&pl[e] = *(const float4*)&pr[e];
    __syncthreads();
    float scale = g[o] / sqrtf(1.f + 1e-5f);
    float beta = be[o];
    const float* tr = tt + ((size_t)b * O + o) * NN;
    float* orow = out + ((size_t)b * O + o) * NN;
    for (int i = threadIdx.x; i < NN; i += 256) {
        float ti = tr[i];
        const int4* ir4 = (const int4*)(idx + (size_t)(b * NN + i) * KK);
        int4 w0 = ir4[0], w1 = ir4[1], w2 = ir4[2], w3 = ir4[3], w4 = ir4[4];
        float m = -__builtin_inff();
        int js[20] = {w0.x, w0.y, w0.z, w0.w, w1.x, w1.y, w1.z, w1.w,
                      w2.x, w2.y, w2.z, w2.w, w3.x, w3.y, w3.z, w3.w,
                      w4.x, w4.y, w4.z, w4.w};
        #pragma unroll
        for (int k = 0; k < KK; ++k) {
            float y = pl[js[k]] + ti;
            m = fmaxf(m, lrelu(fmaf(scale, y, beta)));
        }
        orow[i] = m;
    }
}

// ---------------- transpose W5 [1024][256] -> W5T [256][1024] ----------------
__global__ __launch_bounds__(256) void transpose_kernel(const float* __restrict__ W,
                                                        float* __restrict__ WT) {
    __shared__ float tile[32][33];
    int c0 = blockIdx.x * 32, o0 = blockIdx.y * 32;
    int tx = threadIdx.x, ty = threadIdx.y;
    #pragma unroll
    for (int i = 0; i < 32; i += 8)
        tile[ty + i][tx] = W[(size_t)(o0 + ty + i) * 256 + c0 + tx];
    __syncthreads();
    #pragma unroll
    for (int i = 0; i < 32; i += 8)
        WT[(size_t)(c0 + ty + i) * 1024 + o0 + tx] = tile[tx][ty + i];
}

// ---------------- final: 128x128 block tile, 8x8/thread (R12, proven) -------
__global__ __launch_bounds__(256) void final_kernel(const float* __restrict__ x4,
                                                    const float* __restrict__ W5T,
                                                    const float* __restrict__ g,
                                                    const float* __restrict__ be,
                                                    float* __restrict__ partial) {
    const int CC = 256;
    __shared__ float xs[32][128];
    __shared__ float ws[32][128];
    int blk = blockIdx.x;
    int nb = blk & 15;
    int ob = (blk >> 4) & 7;
    int b  = blk >> 7;
    int t = threadIdx.x;
    int tn = t & 15, to = t >> 4;

    float acc[8][8];
    #pragma unroll
    for (int i = 0; i < 8; ++i)
        #pragma unroll
        for (int j = 0; j < 8; ++j) acc[i][j] = 0.f;

    for (int c0 = 0; c0 < CC; c0 += 32) {
        __syncthreads();
        #pragma unroll
        for (int e = t * 4; e < 32 * 128; e += 1024) {
            int c = e >> 7, n = e & 127;
            *(float4*)&xs[c][n] =
                *(const float4*)&x4[((size_t)b * CC + c0 + c) * NN + nb * 128 + n];
        }
        #pragma unroll
        for (int e = t * 4; e < 32 * 128; e += 1024) {
            int c = e >> 7, o = e & 127;
            *(float4*)&ws[c][o] =
                *(const float4*)&W5T[(size_t)(c0 + c) * 1024 + ob * 128 + o];
        }
        __syncthreads();
        for (int c = 0; c < 32; ++c) {
            float4 xv0 = *(float4*)&xs[c][tn * 4];
            float4 xv1 = *(float4*)&xs[c][64 + tn * 4];
            float4 wv0 = *(float4*)&ws[c][to * 4];
            float4 wv1 = *(float4*)&ws[c][64 + to * 4];
            float xn[8] = {xv0.x, xv0.y, xv0.z, xv0.w, xv1.x, xv1.y, xv1.z, xv1.w};
            float wo[8] = {wv0.x, wv0.y, wv0.z, wv0.w, wv1.x, wv1.y, wv1.z, wv1.w};
            #pragma unroll
            for (int i = 0; i < 8; ++i)
                #pragma unroll
                for (int j = 0; j < 8; ++j)
                    acc[i][j] = fmaf(wo[i], xn[j], acc[i][j]);
        }
    }

    float rs = 1.f / sqrtf(1.f + 1e-5f);
    #pragma unroll
    for (int i = 0; i < 8; ++i) {
        int o = ob * 128 + ((i < 4) ? (to * 4 + i) : (64 + to * 4 + i - 4));
        float scale = g[o] * rs, beta = be[o];
        float m = -__builtin_inff();
        #pragma unroll
        for (int j = 0; j < 8; ++j)
            m = fmaxf(m, lrelu(fmaf(scale, acc[i][j], beta)));
        #pragma unroll
        for (int off = 8; off >= 1; off >>= 1)
            m = fmaxf(m, __shfl_xor(m, off));
        if (tn == 0)
            partial[(size_t)(nb * BB + b) * 1024 + o] = m;
    }
}

__global__ __launch_bounds__(256) void reduce16_kernel(const float* __restrict__ partial,
                                                       float* __restrict__ out) {
    int i = blockIdx.x * 256 + threadIdx.x;
    if (i >= BB * 1024) return;
    int b = i >> 10, o = i & 1023;
    float m = -__builtin_inff();
    #pragma unroll
    for (int nb = 0; nb < 16; ++nb)
        m = fmaxf(m, partial[(size_t)(nb * BB + b) * 1024 + o]);
    out[i] = m;
}

extern "C" void kernel_launch(void* const* d_in, const int* in_sizes, int n_in,
                              void* d_out, int out_size, void* d_ws, size_t ws_size,
                              hipStream_t stream) {
    const float* x  = (const float*)d_in[0];
    const float* W1 = (const float*)d_in[1];
    const float* g1 = (const float*)d_in[2];
    const float* b1 = (const float*)d_in[3];
    const float* W2 = (const float*)d_in[4];
    const float* g2 = (const float*)d_in[5];
    const float* b2 = (const float*)d_in[6];
    const float* W3 = (const float*)d_in[7];
    const float* g3 = (const float*)d_in[8];
    const float* b3 = (const float*)d_in[9];
    const float* W4 = (const float*)d_in[10];
    const float* g4 = (const float*)d_in[11];
    const float* b4 = (const float*)d_in[12];
    const float* W5 = (const float*)d_in[13];
    const float* g5 = (const float*)d_in[14];
    const float* b5 = (const float*)d_in[15];

    float* ws = (float*)d_ws;
    float* sqv     = ws;                       // 8192
    int*   idx     = (int*)(ws + 8192);        // 163840 ints
    float* x1      = ws + 8192 + 163840;       // 524288
    float* x2      = x1 + 524288;              // 524288
    float* x3      = x2 + 524288;              // 1048576
    float* x4      = x3 + 1048576;             // 2097152
    float* p       = x4 + 2097152;             // 2097152
    float* tt      = p + 2097152;              // 2097152
    float* W5T     = p;                        // reuse (dead after layer 4)
    float* partial = tt;                       // reuse

    dim3 blk(256), kblk(512);

    // ---- layer 1: C=3, O=64 ----
    sq_kernel<3><<<32, blk, 0, stream>>>(x, sqv);
    knn_kernel<3><<<BB * (NN / 8), kblk, 0, stream>>>(x, sqv, idx);
    pt_kernel<3, 16><<<BB * 4 * 8, blk, 0, stream>>>(x, W1, p, tt, 64);
    edge_kernel<<<BB * 64, blk, 0, stream>>>(p, tt, idx, g1, b1, x1, 64);

    // ---- layer 2: C=64, O=64 ----
    sq_kernel<64><<<32, blk, 0, stream>>>(x1, sqv);
    knn_kernel<64><<<BB * (NN / 8), kblk, 0, stream>>>(x1, sqv, idx);
    pt_kernel<64, 16><<<BB * 4 * 8, blk, 0, stream>>>(x1, W2, p, tt, 64);
    edge_kernel<<<BB * 64, blk, 0, stream>>>(p, tt, idx, g2, b2, x2, 64);

    // ---- layer 3: C=64, O=128 ----
    sq_kernel<64><<<32, blk, 0, stream>>>(x2, sqv);
    knn_kernel<64><<<BB * (NN / 8), kblk, 0, stream>>>(x2, sqv, idx);
    pt_kernel<64, 16><<<BB * 8 * 8, blk, 0, stream>>>(x2, W3, p, tt, 128);
    edge_kernel<<<BB * 128, blk, 0, stream>>>(p, tt, idx, g3, b3, x3, 128);

    // ---- layer 4: C=128, O=256 ----
    sq_kernel<128><<<32, blk, 0, stream>>>(x3, sqv);
    knn_kernel<128><<<BB * (NN / 8), kblk, 0, stream>>>(x3, sqv, idx);
    pt_kernel<128, 16><<<BB * 16 * 8, blk, 0, stream>>>(x3, W4, p, tt, 256);
    edge_kernel<<<BB * 256, blk, 0, stream>>>(p, tt, idx, g4, b4, x4, 256);

    // ---- layer 5: C=256, O=1024, fused max over n ----
    transpose_kernel<<<dim3(8, 32), dim3(32, 8), 0, stream>>>(W5, W5T);
    final_kernel<<<BB * 8 * 16, blk, 0, stream>>>(x4, W5T, g5, b5, partial);
    reduce16_kernel<<<16, blk, 0, stream>>>(partial, (float*)d_out);
}